// Round 15
// baseline (61.432 us; speedup 1.0000x reference)
//
#include <hip/hip_runtime.h>
#include <hip/hip_bf16.h>

// kernel[i,j] = | prod_{k<16} cos((x[i,k]-y[j,k])/2) |   (f32 in, f32 out)
//
// MFMA formulation (verified r10-r14, absmax 0.00390625): per wire-pair
//   cos(a)cos(b) = 1/2[cos(Rm-Cm) + cos(Rp-Cp)]  -> 4-term separable dot;
// quad (pair x pair) = 16-term dot; out = |Q0 Q1 Q2 Q3|.
// One mfma_f32_32x32x16_bf16 per quad (K=16 exact). Orientation: A=row
// factors, B=col factors => D lane dim = output column (contiguous 128 B
// store segments); reg r -> row (r&3)+8*(r>>2)+4*(lane>>5) [m74/m101].
//
// History: r13 64x64 4blk/CU = 60.59 (best) | r14 128x128 1blk/CU = 61.16
// (staging savings canceled: no co-resident block to overlap phases, tail
// exposed). r15 = middle point: 128x64, 512 blocks = 2 blk/CU. Staging
// sincos-units/CU: 8192 (r13) -> 6144. A-frags reused across 2 col-blocks.
// Packed bf16 cvt (v_cvt_pk_bf16_f32) via __float22bfloat162_rn.

constexpr int D = 16;
constexpr int RSTR = 72;   // LDS row stride in shorts (144 B, 16B-aligned)

typedef short  bf16x8 __attribute__((ext_vector_type(8)));
typedef float  f32x16 __attribute__((ext_vector_type(16)));

static __device__ inline unsigned int pk2(float a, float b) {
    __hip_bfloat162 h = __float22bfloat162_rn(make_float2(a, b));  // lo=a, hi=b
    unsigned int u;
    __builtin_memcpy(&u, &h, 4);
    return u;
}

static __device__ inline void emit_quad(unsigned short* dst, int q,
                                        const float* fa, const float* fb) {
    uint4 lo, hi;
    lo.x = pk2(fa[0] * fb[0], fa[0] * fb[1]);
    lo.y = pk2(fa[0] * fb[2], fa[0] * fb[3]);
    lo.z = pk2(fa[1] * fb[0], fa[1] * fb[1]);
    lo.w = pk2(fa[1] * fb[2], fa[1] * fb[3]);
    hi.x = pk2(fa[2] * fb[0], fa[2] * fb[1]);
    hi.y = pk2(fa[2] * fb[2], fa[2] * fb[3]);
    hi.z = pk2(fa[3] * fb[0], fa[3] * fb[1]);
    hi.w = pk2(fa[3] * fb[2], fa[3] * fb[3]);
    *(uint4*)(dst + q * 16)     = lo;
    *(uint4*)(dst + q * 16 + 8) = hi;
}

__global__ __launch_bounds__(256)
void qkern(const float* __restrict__ x, const float* __restrict__ y,
           float* __restrict__ out, int m) {
    __shared__ unsigned short Al[128 * RSTR];  // row terms: 128 rows x 64 bf16
    __shared__ unsigned short Bl[64 * RSTR];   // col terms: 64 cols x 64 bf16

    const int tid   = threadIdx.x;
    const int row0b = blockIdx.x * 128;
    const int col0b = blockIdx.y * 64;

    // ---- Stage: rows by 128 threads (1/row), cols by 128 threads (2/col). --
    if (tid < 128) {
        const float* src = x + (size_t)(row0b + tid) * D;
        unsigned short* dst = Al + (size_t)tid * RSTR;
        float f[8][4];
#pragma unroll
        for (int p = 0; p < 8; ++p) {
            const float a0 = src[2 * p], a1 = src[2 * p + 1];
            float sm, cm, sp, cp;
            __sincosf(0.5f * (a0 - a1), &sm, &cm);
            __sincosf(0.5f * (a0 + a1), &sp, &cp);
            f[p][0] = 0.5f * cm; f[p][1] = 0.5f * sm;   // 1/2 per pair on rows
            f[p][2] = 0.5f * cp; f[p][3] = 0.5f * sp;
        }
#pragma unroll
        for (int q = 0; q < 4; ++q)
            emit_quad(dst, q, f[2 * q], f[2 * q + 1]);
    } else {
        const int u    = (tid - 128) >> 1;   // col unit 0..63
        const int half = tid & 1;            // pairs 4h..4h+3, quads 2h,2h+1
        const float* src = y + (size_t)(col0b + u) * D;
        unsigned short* dst = Bl + (size_t)u * RSTR;
        float f[4][4];
#pragma unroll
        for (int pp = 0; pp < 4; ++pp) {
            const int p = half * 4 + pp;
            const float a0 = src[2 * p], a1 = src[2 * p + 1];
            float sm, cm, sp, cp;
            __sincosf(0.5f * (a0 - a1), &sm, &cm);
            __sincosf(0.5f * (a0 + a1), &sp, &cp);
            f[pp][0] = cm; f[pp][1] = sm;
            f[pp][2] = cp; f[pp][3] = sp;
        }
#pragma unroll
        for (int qq = 0; qq < 2; ++qq)
            emit_quad(dst, half * 2 + qq, f[2 * qq], f[2 * qq + 1]);
    }
    __syncthreads();

    // ---- MFMA: wave = 32x64 strip (2 tiles of 32x32, shared A-frags). ----
    const int wave = tid >> 6;
    const int lane = tid & 63;
    const int l31  = lane & 31;
    const int kh   = lane >> 5;          // k-half
    const int rw   = wave * 32;          // strip row base within tile

    const f32x16 zc = {0.f};

    bf16x8 af[4];
#pragma unroll
    for (int q = 0; q < 4; ++q)
        af[q] = *(const bf16x8*)(Al + (size_t)(rw + l31) * RSTR + q * 16 + kh * 8);

#pragma unroll
    for (int cb = 0; cb < 2; ++cb) {
        const int cw = cb * 32;
        f32x16 prod;
        {
            const bf16x8 b0 = *(const bf16x8*)(Bl + (size_t)(cw + l31) * RSTR + kh * 8);
            prod = __builtin_amdgcn_mfma_f32_32x32x16_bf16(af[0], b0, zc, 0, 0, 0);
        }
#pragma unroll
        for (int q = 1; q < 4; ++q) {
            const bf16x8 bq = *(const bf16x8*)(Bl + (size_t)(cw + l31) * RSTR + q * 16 + kh * 8);
            const f32x16 acc = __builtin_amdgcn_mfma_f32_32x32x16_bf16(af[q], bq, zc, 0, 0, 0);
            prod *= acc;
        }

        // Epilogue: reg r -> row = rw + (r&3)+8*(r>>2)+4*kh; col = cw + l31.
        float* base = out + (size_t)(row0b + rw + 4 * kh) * m + col0b + cw + l31;
#pragma unroll
        for (int r = 0; r < 16; ++r) {
            const int row_off = (r & 3) + 8 * (r >> 2);
            __builtin_nontemporal_store(fabsf(prod[r]), base + (size_t)row_off * m);
        }
    }
}

extern "C" void kernel_launch(void* const* d_in, const int* in_sizes, int n_in,
                              void* d_out, int out_size, void* d_ws, size_t ws_size,
                              hipStream_t stream) {
    const float* x = (const float*)d_in[0];
    const float* y = (const float*)d_in[1];
    float* out = (float*)d_out;
    const int n = in_sizes[0] / D;   // 2048
    const int m = in_sizes[1] / D;   // 2048

    dim3 grid(n / 128, m / 64);      // 16 x 32 = 512 blocks -> 2 blk/CU
    qkern<<<grid, 256, 0, stream>>>(x, y, out, m);
}